// Round 1
// baseline (538.408 us; speedup 1.0000x reference)
//
#include <hip/hip_runtime.h>

typedef short short8 __attribute__((ext_vector_type(8)));
typedef unsigned short u16x8 __attribute__((ext_vector_type(8)));
typedef float f32x4 __attribute__((ext_vector_type(4)));

#define AS1 __attribute__((address_space(1)))
#define AS3 __attribute__((address_space(3)))

__device__ __forceinline__ void gload16(const void* g, void* l) {
  __builtin_amdgcn_global_load_lds((AS1 void*)g, (AS3 void*)l, 16, 0, 0);
}

__device__ __forceinline__ unsigned short f2bf(float f) {
  unsigned u = __float_as_uint(f);
  u = (u + 0x7FFF + ((u >> 16) & 1)) >> 16;  // RNE
  return (unsigned short)u;
}
__device__ __forceinline__ float bf2f(unsigned short u) {
  return __uint_as_float(((unsigned)u) << 16);
}

// ---------------- conversion kernels ----------------
__global__ void cvt_x_kernel(const float4* __restrict__ in, ushort4* __restrict__ out, int n4) {
  int i = blockIdx.x * 256 + threadIdx.x;
  if (i >= n4) return;
  float4 v = in[i];
  ushort4 o;
  o.x = f2bf(v.x); o.y = f2bf(v.y); o.z = f2bf(v.z); o.w = f2bf(v.w);
  out[i] = o;
}

// W [512][512] row-major (k,n) -> Wt bf16 [n][k]
__global__ void cvt_wt_kernel(const float* __restrict__ W, unsigned short* __restrict__ Wt) {
  int idx = blockIdx.x * 256 + threadIdx.x;
  if (idx >= 512 * 512) return;
  int k = idx >> 9, n = idx & 511;
  Wt[n * 512 + k] = f2bf(W[idx]);
}

// ---------------- edge dtype detector ----------------
__global__ void detect64_kernel(const int* __restrict__ ei32, int* __restrict__ flag) {
  if (blockIdx.x == 0 && threadIdx.x == 0) {
    int f = 1;
    for (int i = 0; i < 64; ++i)
      if (ei32[2 * i + 1] != 0) { f = 0; break; }
    *flag = f;
  }
}

// ---------------- CSR build ----------------
__global__ void count_kernel(const int* __restrict__ ei32, const int* __restrict__ flag,
                             int* __restrict__ cnt, int E) {
  int e = blockIdx.x * 256 + threadIdx.x;
  if (e >= E) return;
  int c = (*flag) ? ei32[2 * E + 2 * e] : ei32[E + e];
  atomicAdd(&cnt[c], 1);
}

__global__ void __launch_bounds__(1024) scan_kernel(const int* __restrict__ cnt,
    int* __restrict__ ptr, int* __restrict__ cur, float* __restrict__ dis, int n) {
  __shared__ int wsum[16];
  __shared__ int cbase;
  const int tid = threadIdx.x;
  const int lane = tid & 63, wid = tid >> 6;
  if (tid == 0) cbase = 0;
  __syncthreads();
  const int nChunks = (n + 1023) >> 10;
  for (int c = 0; c < nChunks; ++c) {
    const int i = (c << 10) + tid;
    const int v = (i < n) ? cnt[i] : 0;
    int x = v;
#pragma unroll
    for (int d = 1; d < 64; d <<= 1) {
      int y = __shfl_up(x, d, 64);
      if (lane >= d) x += y;
    }
    if (lane == 63) wsum[wid] = x;
    __syncthreads();
    if (tid < 16) {
      int wv = wsum[tid];
      int wx = wv;
#pragma unroll
      for (int d = 1; d < 16; d <<= 1) {
        int y = __shfl_up(wx, d, 64);
        if (tid >= d) wx += y;
      }
      wsum[tid] = wx - wv;  // exclusive wave offset
    }
    __syncthreads();
    const int base = cbase;
    const int excl = base + wsum[wid] + (x - v);
    if (i < n) {
      ptr[i] = excl;
      cur[i] = excl;
      dis[i] = rsqrtf((float)(v + 1));  // +1 self-loop, deg >= 1 always
    }
    __syncthreads();
    if (tid == 1023) cbase = excl + v;
    __syncthreads();
  }
  if (tid == 0) ptr[n] = cbase;
}

__global__ void fill_kernel(const int* __restrict__ ei32, const int* __restrict__ flag,
                            int* __restrict__ cur, int* __restrict__ eidx, int E) {
  int e = blockIdx.x * 256 + threadIdx.x;
  if (e >= E) return;
  int is64 = *flag;
  int r = is64 ? ei32[2 * e] : ei32[e];
  int c = is64 ? ei32[2 * E + 2 * e] : ei32[E + e];
  int pos = atomicAdd(&cur[c], 1);
  eidx[pos] = r;
}

// ---------------- bf16 MFMA GEMM: C[M][512] = A[M][512] @ Bt[n][k]^T ----------------
// 128x128 tile, BK=32, 256 threads (2x2 waves of 64x64), m97-style global_load_lds staging.
__global__ void __launch_bounds__(256) gemm_kernel(const unsigned short* __restrict__ A,
                                                   const unsigned short* __restrict__ Bt,
                                                   unsigned short* __restrict__ C, int M) {
  __shared__ alignas(128) unsigned short As[4096];  // [128 rows][32 k] bf16
  __shared__ alignas(128) unsigned short Bs[4096];  // [128 n]  [32 k]
  const int tid = threadIdx.x;
  const int wave = tid >> 6;
  const int lane = tid & 63;
  const int wm = wave >> 1, wn = wave & 1;
  const int bm = blockIdx.x, bn = blockIdx.y;

  const int lr = lane >> 2;   // staging: row within 16-row chunk
  const int ls = lane & 3;    // staging: 16B slot within 64B row
  const int fr = lane & 15;   // frag: row/col
  const int ks = lane >> 4;   // frag: k-slot (8 elems)

  f32x4 acc[4][4] = {};

  for (int kt = 0; kt < 16; ++kt) {
    __syncthreads();
#pragma unroll
    for (int p = 0; p < 2; ++p) {
      const int q = p * 4 + wave;          // 1KB chunk id, 0..7
      int ra = bm * 128 + q * 16 + lr;
      ra = ra < M ? ra : M - 1;            // clamp tail rows
      gload16(A + (size_t)ra * 512 + kt * 32 + ls * 8, &As[q * 512]);
      const int rb = bn * 128 + q * 16 + lr;
      gload16(Bt + (size_t)rb * 512 + kt * 32 + ls * 8, &Bs[q * 512]);
    }
    __syncthreads();

    short8 af[4], bfr[4];
#pragma unroll
    for (int m = 0; m < 4; ++m)
      af[m] = *(const short8*)&As[(wm * 64 + m * 16 + fr) * 32 + ks * 8];
#pragma unroll
    for (int n = 0; n < 4; ++n)
      bfr[n] = *(const short8*)&Bs[(wn * 64 + n * 16 + fr) * 32 + ks * 8];
#pragma unroll
    for (int m = 0; m < 4; ++m)
#pragma unroll
      for (int n = 0; n < 4; ++n)
        acc[m][n] = __builtin_amdgcn_mfma_f32_16x16x32_bf16(af[m], bfr[n], acc[m][n], 0, 0, 0);
  }

  // epilogue: D row = (lane>>4)*4 + reg, col = lane&15
  const int rbase = bm * 128 + wm * 64 + (lane >> 4) * 4;
  const int cbase = bn * 128 + wn * 64 + (lane & 15);
#pragma unroll
  for (int m = 0; m < 4; ++m)
#pragma unroll
    for (int n = 0; n < 4; ++n)
#pragma unroll
      for (int j = 0; j < 4; ++j) {
        int r = rbase + m * 16 + j;
        if (r < M) C[(size_t)r * 512 + cbase + n * 16] = f2bf(acc[m][n][j]);
      }
}

// ---------------- aggregation: one wave per node ----------------
// out[i] = sum_{e in in(i)} h[src]*dis[src]*dis[i] + h[i]*dis[i]^2 + b  (then relu+bf16 if !FINAL)
template <bool FINAL>
__global__ void agg_kernel(const unsigned short* __restrict__ h, const int* __restrict__ eidx,
                           const int* __restrict__ ptr, const float* __restrict__ dis,
                           const float* __restrict__ bias, void* __restrict__ outv, int n) {
  const int lane = threadIdx.x & 63;
  const int node = (blockIdx.x << 2) + (threadIdx.x >> 6);
  if (node >= n) return;
  const int fbase = lane << 3;  // 8 features per lane

  float acc[8] = {0, 0, 0, 0, 0, 0, 0, 0};
  const float di = dis[node];
  const int start = ptr[node], end = ptr[node + 1];

#pragma unroll 2
  for (int e = start; e < end; ++e) {
    const int src = eidx[e];
    const float nrm = dis[src] * di;
    const u16x8 v = *(const u16x8*)(h + (size_t)src * 512 + fbase);
#pragma unroll
    for (int j = 0; j < 8; ++j) acc[j] += bf2f(v[j]) * nrm;
  }
  {  // self loop
    const u16x8 v = *(const u16x8*)(h + (size_t)node * 512 + fbase);
    const float nrm = di * di;
#pragma unroll
    for (int j = 0; j < 8; ++j) acc[j] += bf2f(v[j]) * nrm;
  }

  float b[8];
  *(float4*)&b[0] = *(const float4*)(bias + fbase);
  *(float4*)&b[4] = *(const float4*)(bias + fbase + 4);

  if (FINAL) {
    float* out = (float*)outv;
    float4 o0, o1;
    o0.x = acc[0] + b[0]; o0.y = acc[1] + b[1]; o0.z = acc[2] + b[2]; o0.w = acc[3] + b[3];
    o1.x = acc[4] + b[4]; o1.y = acc[5] + b[5]; o1.z = acc[6] + b[6]; o1.w = acc[7] + b[7];
    *(float4*)(out + (size_t)node * 512 + fbase) = o0;
    *(float4*)(out + (size_t)node * 512 + fbase + 4) = o1;
  } else {
    unsigned short* out = (unsigned short*)outv;
    u16x8 o;
#pragma unroll
    for (int j = 0; j < 8; ++j) {
      float v = acc[j] + b[j];
      o[j] = f2bf(v > 0.0f ? v : 0.0f);
    }
    *(u16x8*)(out + (size_t)node * 512 + fbase) = o;
  }
}

// ---------------- launch ----------------
extern "C" void kernel_launch(void* const* d_in, const int* in_sizes, int n_in,
                              void* d_out, int out_size, void* d_ws, size_t ws_size,
                              hipStream_t stream) {
  const float* x  = (const float*)d_in[0];
  const int*   ei = (const int*)d_in[1];
  const float* W1 = (const float*)d_in[2];
  const float* b1 = (const float*)d_in[3];
  const float* W2 = (const float*)d_in[4];
  const float* b2 = (const float*)d_in[5];
  float* out = (float*)d_out;

  const int M = in_sizes[0] / 512;  // 50000
  const int E = in_sizes[1] / 2;    // 800000

  auto alignup = [](size_t v) { return (v + 255) & ~(size_t)255; };
  char* p = (char*)d_ws;
  unsigned short* xb  = (unsigned short*)p; p += alignup((size_t)M * 512 * 2);
  unsigned short* h1b = (unsigned short*)p; p += alignup((size_t)M * 512 * 2);
  unsigned short* r1b = (unsigned short*)p; p += alignup((size_t)M * 512 * 2);
  unsigned short* w1b = (unsigned short*)p; p += alignup(512 * 512 * 2);
  unsigned short* w2b = (unsigned short*)p; p += alignup(512 * 512 * 2);
  float* dis = (float*)p; p += alignup((size_t)M * 4);
  int* cnt   = (int*)p;   p += alignup((size_t)M * 4);
  int* ptr   = (int*)p;   p += alignup((size_t)(M + 1) * 4);
  int* cur   = (int*)p;   p += alignup((size_t)M * 4);
  int* eidx  = (int*)p;   p += alignup((size_t)E * 4);
  int* flag  = (int*)p;   p += alignup(256);
  unsigned short* h2b = xb;  // reuse (xb dead after GEMM1)

  hipMemsetAsync(cnt, 0, (size_t)M * 4, stream);
  detect64_kernel<<<1, 64, 0, stream>>>(ei, flag);

  cvt_x_kernel<<<(M * 128 + 255) / 256, 256, 0, stream>>>((const float4*)x, (ushort4*)xb, M * 128);
  cvt_wt_kernel<<<1024, 256, 0, stream>>>(W1, w1b);
  cvt_wt_kernel<<<1024, 256, 0, stream>>>(W2, w2b);

  count_kernel<<<(E + 255) / 256, 256, 0, stream>>>(ei, flag, cnt, E);
  scan_kernel<<<1, 1024, 0, stream>>>(cnt, ptr, cur, dis, M);
  fill_kernel<<<(E + 255) / 256, 256, 0, stream>>>(ei, flag, cur, eidx, E);

  dim3 gg((M + 127) / 128, 4);
  gemm_kernel<<<gg, 256, 0, stream>>>(xb, w1b, h1b, M);
  agg_kernel<false><<<(M + 3) / 4, 256, 0, stream>>>(h1b, eidx, ptr, dis, b1, (void*)r1b, M);
  gemm_kernel<<<gg, 256, 0, stream>>>(r1b, w2b, h2b, M);
  agg_kernel<true><<<(M + 3) / 4, 256, 0, stream>>>(h2b, eidx, ptr, dis, b2, (void*)out, M);
}

// Round 2
// 494.258 us; speedup vs baseline: 1.0893x; 1.0893x over previous
//
#include <hip/hip_runtime.h>

typedef short short8 __attribute__((ext_vector_type(8)));
typedef unsigned short u16x8 __attribute__((ext_vector_type(8)));
typedef float f32x4 __attribute__((ext_vector_type(4)));

#define AS1 __attribute__((address_space(1)))
#define AS3 __attribute__((address_space(3)))

__device__ __forceinline__ void gload16(const void* g, void* l) {
  __builtin_amdgcn_global_load_lds((AS1 void*)g, (AS3 void*)l, 16, 0, 0);
}

__device__ __forceinline__ unsigned short f2bf(float f) {
  unsigned u = __float_as_uint(f);
  u = (u + 0x7FFF + ((u >> 16) & 1)) >> 16;  // RNE
  return (unsigned short)u;
}
__device__ __forceinline__ float bf2f(unsigned short u) {
  return __uint_as_float(((unsigned)u) << 16);
}

// ---------------- conversion kernels ----------------
__global__ void cvt_x_kernel(const float4* __restrict__ in, ushort4* __restrict__ out, int n4) {
  int i = blockIdx.x * 256 + threadIdx.x;
  if (i >= n4) return;
  float4 v = in[i];
  ushort4 o;
  o.x = f2bf(v.x); o.y = f2bf(v.y); o.z = f2bf(v.z); o.w = f2bf(v.w);
  out[i] = o;
}

// W [512][512] row-major (k,n) -> Wt bf16 [n][k]
__global__ void cvt_wt_kernel(const float* __restrict__ W, unsigned short* __restrict__ Wt) {
  int idx = blockIdx.x * 256 + threadIdx.x;
  if (idx >= 512 * 512) return;
  int k = idx >> 9, n = idx & 511;
  Wt[n * 512 + k] = f2bf(W[idx]);
}

// ---------------- edge dtype detector ----------------
__global__ void detect64_kernel(const int* __restrict__ ei32, int* __restrict__ flag) {
  if (blockIdx.x == 0 && threadIdx.x == 0) {
    int f = 1;
    for (int i = 0; i < 64; ++i)
      if (ei32[2 * i + 1] != 0) { f = 0; break; }
    *flag = f;
  }
}

// ---------------- CSR build ----------------
__global__ void count_kernel(const int* __restrict__ ei32, const int* __restrict__ flag,
                             int* __restrict__ cnt, int E) {
  int e = blockIdx.x * 256 + threadIdx.x;
  if (e >= E) return;
  int c = (*flag) ? ei32[2 * E + 2 * e] : ei32[E + e];
  atomicAdd(&cnt[c], 1);
}

// hierarchical scan: (1) per-block sums, (2) 1-wave scan of block sums, (3) fill
__global__ void __launch_bounds__(1024) scan_bsum_kernel(const int* __restrict__ cnt,
                                                         int* __restrict__ bsum, int n) {
  __shared__ int ws[16];
  const int tid = threadIdx.x, lane = tid & 63, wid = tid >> 6;
  const int i = blockIdx.x * 1024 + tid;
  int x = (i < n) ? cnt[i] : 0;
#pragma unroll
  for (int d = 1; d < 64; d <<= 1) x += __shfl_xor(x, d, 64);
  if (lane == 0) ws[wid] = x;
  __syncthreads();
  if (tid == 0) {
    int s = 0;
#pragma unroll
    for (int w = 0; w < 16; ++w) s += ws[w];
    bsum[blockIdx.x] = s;
  }
}

__global__ void scan_boff_kernel(int* __restrict__ bsum, int* __restrict__ ptrN, int B) {
  const int lane = threadIdx.x;
  const int v = (lane < B) ? bsum[lane] : 0;
  int x = v;
#pragma unroll
  for (int d = 1; d < 64; d <<= 1) {
    int y = __shfl_up(x, d, 64);
    if (lane >= d) x += y;
  }
  if (lane < B) bsum[lane] = x - v;  // exclusive block offset
  if (lane == B - 1) *ptrN = x;      // grand total
}

__global__ void __launch_bounds__(1024) scan_fill_kernel(const int* __restrict__ cnt,
    const int* __restrict__ boff, int* __restrict__ ptr, int* __restrict__ cur,
    float* __restrict__ dis, int n) {
  __shared__ int ws[16];
  const int tid = threadIdx.x, lane = tid & 63, wid = tid >> 6;
  const int i = blockIdx.x * 1024 + tid;
  const int v = (i < n) ? cnt[i] : 0;
  int x = v;
#pragma unroll
  for (int d = 1; d < 64; d <<= 1) {
    int y = __shfl_up(x, d, 64);
    if (lane >= d) x += y;
  }
  if (lane == 63) ws[wid] = x;
  __syncthreads();
  if (tid < 16) {
    int wv = ws[tid];
    int wx = wv;
#pragma unroll
    for (int d = 1; d < 16; d <<= 1) {
      int y = __shfl_up(wx, d, 64);
      if (tid >= d) wx += y;
    }
    ws[tid] = wx - wv;  // exclusive wave offset
  }
  __syncthreads();
  if (i < n) {
    const int excl = boff[blockIdx.x] + ws[wid] + (x - v);
    ptr[i] = excl;
    cur[i] = excl;
    dis[i] = rsqrtf((float)(v + 1));  // +1 self-loop
  }
}

__global__ void fill_kernel(const int* __restrict__ ei32, const int* __restrict__ flag,
                            int* __restrict__ cur, int* __restrict__ eidx, int E) {
  int e = blockIdx.x * 256 + threadIdx.x;
  if (e >= E) return;
  int is64 = *flag;
  int r = is64 ? ei32[2 * e] : ei32[e];
  int c = is64 ? ei32[2 * E + 2 * e] : ei32[E + e];
  int pos = atomicAdd(&cur[c], 1);
  eidx[pos] = r;
}

// ---------------- bf16 MFMA GEMM: C[M][512] = A[M][512] @ Bt[n][k]^T ----------------
__global__ void __launch_bounds__(256) gemm_kernel(const unsigned short* __restrict__ A,
                                                   const unsigned short* __restrict__ Bt,
                                                   unsigned short* __restrict__ C, int M) {
  __shared__ alignas(128) unsigned short As[4096];  // [128 rows][32 k] bf16
  __shared__ alignas(128) unsigned short Bs[4096];  // [128 n]  [32 k]
  const int tid = threadIdx.x;
  const int wave = tid >> 6;
  const int lane = tid & 63;
  const int wm = wave >> 1, wn = wave & 1;
  const int bm = blockIdx.x, bn = blockIdx.y;

  const int lr = lane >> 2;
  const int ls = lane & 3;
  const int fr = lane & 15;
  const int ks = lane >> 4;

  f32x4 acc[4][4] = {};

  for (int kt = 0; kt < 16; ++kt) {
    __syncthreads();
#pragma unroll
    for (int p = 0; p < 2; ++p) {
      const int q = p * 4 + wave;
      int ra = bm * 128 + q * 16 + lr;
      ra = ra < M ? ra : M - 1;
      gload16(A + (size_t)ra * 512 + kt * 32 + ls * 8, &As[q * 512]);
      const int rb = bn * 128 + q * 16 + lr;
      gload16(Bt + (size_t)rb * 512 + kt * 32 + ls * 8, &Bs[q * 512]);
    }
    __syncthreads();

    short8 af[4], bfr[4];
#pragma unroll
    for (int m = 0; m < 4; ++m)
      af[m] = *(const short8*)&As[(wm * 64 + m * 16 + fr) * 32 + ks * 8];
#pragma unroll
    for (int n = 0; n < 4; ++n)
      bfr[n] = *(const short8*)&Bs[(wn * 64 + n * 16 + fr) * 32 + ks * 8];
#pragma unroll
    for (int m = 0; m < 4; ++m)
#pragma unroll
      for (int n = 0; n < 4; ++n)
        acc[m][n] = __builtin_amdgcn_mfma_f32_16x16x32_bf16(af[m], bfr[n], acc[m][n], 0, 0, 0);
  }

  const int rbase = bm * 128 + wm * 64 + (lane >> 4) * 4;
  const int cbase = bn * 128 + wn * 64 + (lane & 15);
#pragma unroll
  for (int m = 0; m < 4; ++m)
#pragma unroll
    for (int n = 0; n < 4; ++n)
#pragma unroll
      for (int j = 0; j < 4; ++j) {
        int r = rbase + m * 16 + j;
        if (r < M) C[(size_t)r * 512 + cbase + n * 16] = f2bf(acc[m][n][j]);
      }
}

// ---------------- aggregation: one wave per node, pipelined gathers ----------------
template <bool FINAL>
__global__ void __launch_bounds__(256) agg_kernel(const unsigned short* __restrict__ h,
    const int* __restrict__ eidx, const int* __restrict__ ptr, const float* __restrict__ dis,
    const float* __restrict__ bias, void* __restrict__ outv, int n) {
  const int lane = threadIdx.x & 63;
  const int node = (blockIdx.x << 2) + (threadIdx.x >> 6);
  if (node >= n) return;
  const int fbase = lane << 3;  // 8 features per lane

  float acc[8] = {0, 0, 0, 0, 0, 0, 0, 0};
  const float di = dis[node];
  const int start = ptr[node];
  const int deg = ptr[node + 1] - start;

  {  // self loop
    const u16x8 v = *(const u16x8*)(h + (size_t)node * 512 + fbase);
    const float nrm = di * di;
#pragma unroll
    for (int j = 0; j < 8; ++j) acc[j] += bf2f(v[j]) * nrm;
  }

  for (int base = 0; base < deg; base += 64) {
    const int cnt = min(deg - base, 64);
    int src_l = 0;
    float nrm_l = 0.0f;
    if (lane < cnt) {
      src_l = eidx[start + base + lane];
      nrm_l = dis[src_l] * di;
    }
    int e = 0;
    // 8-deep independent gather pipeline: broadcast via v_readlane (SGPR base
    // per row -> zero per-edge VALU address math), issue 8 loads, then FMA.
    for (; e + 8 <= cnt; e += 8) {
      int s[8];
      float nn[8];
      u16x8 vb[8];
#pragma unroll
      for (int k = 0; k < 8; ++k) {
        s[k] = __builtin_amdgcn_readlane(src_l, e + k);
        nn[k] = __int_as_float(__builtin_amdgcn_readlane(__float_as_int(nrm_l), e + k));
      }
#pragma unroll
      for (int k = 0; k < 8; ++k)
        vb[k] = *(const u16x8*)(h + (size_t)(unsigned)s[k] * 512 + fbase);
#pragma unroll
      for (int k = 0; k < 8; ++k)
#pragma unroll
        for (int j = 0; j < 8; ++j) acc[j] += bf2f(vb[k][j]) * nn[k];
    }
    for (; e + 4 <= cnt; e += 4) {
      int s[4];
      float nn[4];
      u16x8 vb[4];
#pragma unroll
      for (int k = 0; k < 4; ++k) {
        s[k] = __builtin_amdgcn_readlane(src_l, e + k);
        nn[k] = __int_as_float(__builtin_amdgcn_readlane(__float_as_int(nrm_l), e + k));
      }
#pragma unroll
      for (int k = 0; k < 4; ++k)
        vb[k] = *(const u16x8*)(h + (size_t)(unsigned)s[k] * 512 + fbase);
#pragma unroll
      for (int k = 0; k < 4; ++k)
#pragma unroll
        for (int j = 0; j < 8; ++j) acc[j] += bf2f(vb[k][j]) * nn[k];
    }
    for (; e < cnt; ++e) {
      const int s0 = __builtin_amdgcn_readlane(src_l, e);
      const float n0 = __int_as_float(__builtin_amdgcn_readlane(__float_as_int(nrm_l), e));
      const u16x8 v = *(const u16x8*)(h + (size_t)(unsigned)s0 * 512 + fbase);
#pragma unroll
      for (int j = 0; j < 8; ++j) acc[j] += bf2f(v[j]) * n0;
    }
  }

  float b[8];
  *(float4*)&b[0] = *(const float4*)(bias + fbase);
  *(float4*)&b[4] = *(const float4*)(bias + fbase + 4);

  if (FINAL) {
    float* out = (float*)outv;
    float4 o0, o1;
    o0.x = acc[0] + b[0]; o0.y = acc[1] + b[1]; o0.z = acc[2] + b[2]; o0.w = acc[3] + b[3];
    o1.x = acc[4] + b[4]; o1.y = acc[5] + b[5]; o1.z = acc[6] + b[6]; o1.w = acc[7] + b[7];
    *(float4*)(out + (size_t)node * 512 + fbase) = o0;
    *(float4*)(out + (size_t)node * 512 + fbase + 4) = o1;
  } else {
    unsigned short* out = (unsigned short*)outv;
    u16x8 o;
#pragma unroll
    for (int j = 0; j < 8; ++j) {
      float v = acc[j] + b[j];
      o[j] = f2bf(v > 0.0f ? v : 0.0f);
    }
    *(u16x8*)(out + (size_t)node * 512 + fbase) = o;
  }
}

// ---------------- launch ----------------
extern "C" void kernel_launch(void* const* d_in, const int* in_sizes, int n_in,
                              void* d_out, int out_size, void* d_ws, size_t ws_size,
                              hipStream_t stream) {
  const float* x  = (const float*)d_in[0];
  const int*   ei = (const int*)d_in[1];
  const float* W1 = (const float*)d_in[2];
  const float* b1 = (const float*)d_in[3];
  const float* W2 = (const float*)d_in[4];
  const float* b2 = (const float*)d_in[5];
  float* out = (float*)d_out;

  const int M = in_sizes[0] / 512;  // 50000
  const int E = in_sizes[1] / 2;    // 800000

  auto alignup = [](size_t v) { return (v + 255) & ~(size_t)255; };
  char* p = (char*)d_ws;
  unsigned short* xb  = (unsigned short*)p; p += alignup((size_t)M * 512 * 2);
  unsigned short* h1b = (unsigned short*)p; p += alignup((size_t)M * 512 * 2);
  unsigned short* r1b = (unsigned short*)p; p += alignup((size_t)M * 512 * 2);
  unsigned short* w1b = (unsigned short*)p; p += alignup(512 * 512 * 2);
  unsigned short* w2b = (unsigned short*)p; p += alignup(512 * 512 * 2);
  float* dis = (float*)p; p += alignup((size_t)M * 4);
  int* cnt   = (int*)p;   p += alignup((size_t)M * 4);
  int* ptr   = (int*)p;   p += alignup((size_t)(M + 1) * 4);
  int* cur   = (int*)p;   p += alignup((size_t)M * 4);
  int* eidx  = (int*)p;   p += alignup((size_t)E * 4);
  int* flag  = (int*)p;   p += alignup(256);
  int* bsum  = (int*)p;   p += alignup(1024);
  unsigned short* h2b = xb;  // reuse (xb dead after GEMM1)

  hipMemsetAsync(cnt, 0, (size_t)M * 4, stream);
  detect64_kernel<<<1, 64, 0, stream>>>(ei, flag);

  cvt_x_kernel<<<(M * 128 + 255) / 256, 256, 0, stream>>>((const float4*)x, (ushort4*)xb, M * 128);
  cvt_wt_kernel<<<1024, 256, 0, stream>>>(W1, w1b);
  cvt_wt_kernel<<<1024, 256, 0, stream>>>(W2, w2b);

  count_kernel<<<(E + 255) / 256, 256, 0, stream>>>(ei, flag, cnt, E);
  const int B = (M + 1023) / 1024;
  scan_bsum_kernel<<<B, 1024, 0, stream>>>(cnt, bsum, M);
  scan_boff_kernel<<<1, 64, 0, stream>>>(bsum, ptr + M, B);
  scan_fill_kernel<<<B, 1024, 0, stream>>>(cnt, bsum, ptr, cur, dis, M);
  fill_kernel<<<(E + 255) / 256, 256, 0, stream>>>(ei, flag, cur, eidx, E);

  dim3 gg((M + 127) / 128, 4);
  gemm_kernel<<<gg, 256, 0, stream>>>(xb, w1b, h1b, M);
  agg_kernel<false><<<(M + 3) / 4, 256, 0, stream>>>(h1b, eidx, ptr, dis, b1, (void*)r1b, M);
  gemm_kernel<<<gg, 256, 0, stream>>>(r1b, w2b, h2b, M);
  agg_kernel<true><<<(M + 3) / 4, 256, 0, stream>>>(h2b, eidx, ptr, dis, b2, (void*)out, M);
}